// Round 3
// baseline (2020.084 us; speedup 1.0000x reference)
//
#include <hip/hip_runtime.h>
#include <math.h>

#ifndef M_PI
#define M_PI 3.14159265358979323846
#endif

#define LEN   4096
#define NB    32
#define NH    64
#define NF    2048   // modes stored (bins 0..2047)
#define NLAYER 4

// ---------------------------------------------------------------------------
// twiddle table: tw[k] = exp(-2*pi*i*k/4096), k = 0..2047
__global__ __launch_bounds__(256) void fill_tw(float2* __restrict__ tw) {
    int k = blockIdx.x * 256 + threadIdx.x;
    if (k < 2048) {
        double ang = -2.0 * M_PI * (double)k / 4096.0;
        tw[k] = make_float2((float)cos(ang), (float)sin(ang));
    }
}

// ---------------------------------------------------------------------------
// encoder
__global__ __launch_bounds__(256) void encoder_k(
        const float* __restrict__ x, const float* __restrict__ u,
        const float* __restrict__ ew, const float* __restrict__ eb,
        float* __restrict__ v) {
    int tid = blockIdx.x * 256 + threadIdx.x;
    int b = tid >> 12;
    int l = tid & (LEN - 1);
    float xv = x[(size_t)b * LEN + l];
    float u0 = u[((size_t)b * 3 + 0) * LEN + l];
    float u1 = u[((size_t)b * 3 + 1) * LEN + l];
    float u2 = u[((size_t)b * 3 + 2) * LEN + l];
    for (int h = 0; h < NH; ++h) {
        float a = eb[h] + ew[h*4+0]*xv + ew[h*4+1]*u0 + ew[h*4+2]*u1 + ew[h*4+3]*u2;
        v[((size_t)b * NH + h) * LEN + l] = a;
    }
}

// ---------------------------------------------------------------------------
// forward FFT, REAL-PAIR PACKED: block p handles rows 2p, 2p+1.
// Output is ROW-MAJOR: Xt[row][f], f = 0..2047 (directly consumed by specmm).
__global__ __launch_bounds__(256) void fft_fwd_k(
        const float* __restrict__ vin, float2* __restrict__ Xt,
        const float2* __restrict__ tw) {
    __shared__ float2 a[4096];
    int p = blockIdx.x;                          // 0..1023
    const float* s1 = vin + (size_t)(2*p)   * LEN;
    const float* s2 = vin + (size_t)(2*p+1) * LEN;
    int t = threadIdx.x;
    for (int j = 0; j < 16; ++j) {
        int idx = t + j * 256;
        int r = __brev((unsigned)idx) >> 20;
        a[r] = make_float2(s1[idx], s2[idx]);
    }
    __syncthreads();
    for (int s = 1; s <= 12; ++s) {
        int half = 1 << (s - 1);
        int tws  = 12 - s;
        for (int j = t; j < 2048; j += 256) {
            int k = j & (half - 1);
            int base = ((j >> (s - 1)) << s) + k;
            float2 w  = tw[k << tws];
            float2 x0 = a[base];
            float2 x1 = a[base + half];
            float tr = w.x * x1.x - w.y * x1.y;
            float ti = w.x * x1.y + w.y * x1.x;
            a[base]        = make_float2(x0.x + tr, x0.y + ti);
            a[base + half] = make_float2(x0.x - tr, x0.y - ti);
        }
        __syncthreads();
    }
    float2* d1 = Xt + (size_t)(2*p)   * NF;
    float2* d2 = Xt + (size_t)(2*p+1) * NF;
    for (int j = 0; j < 8; ++j) {
        int f = t + j * 256;                     // 0..2047
        float2 Zf = a[f];
        float2 Zm = a[(4096 - f) & 4095];
        d1[f] = make_float2(0.5f * (Zf.x + Zm.x), 0.5f * (Zf.y - Zm.y));
        d2[f] = make_float2(0.5f * (Zf.y + Zm.y), 0.5f * (Zm.x - Zf.x));
    }
}

// ---------------------------------------------------------------------------
// inverse FFT, REAL-PAIR PACKED: block p produces rows 2p, 2p+1.
// Input is ROW-MAJOR: Yt[row][f] (directly produced by specmm).
__global__ __launch_bounds__(256) void fft_inv_k(
        const float2* __restrict__ Yt, float* __restrict__ sout,
        const float2* __restrict__ tw,
        const float* __restrict__ sb0, const float* __restrict__ sb1,
        const float* __restrict__ sb2, int layer) {
    __shared__ float2 a[4096];
    int p = blockIdx.x;                          // 0..1023
    int o = (2 * p) & (NH - 1);                  // even o
    const float2* s1 = Yt + (size_t)(2*p)   * NF;
    const float2* s2 = Yt + (size_t)(2*p+1) * NF;
    int t = threadIdx.x;
    for (int j = 0; j < 8; ++j) {
        int f = t + j * 256;                     // 0..2047
        float2 y1 = s1[f];
        float2 y2 = s2[f];
        float2 z;
        if (f == 0) z = make_float2(y1.x, y2.x);
        else        z = make_float2(y1.x - y2.y, y1.y + y2.x);
        a[__brev((unsigned)f) >> 20] = z;
    }
    for (int j = 0; j < 8; ++j) {
        int f = 2048 + t + j * 256;              // 2048..4095
        float2 z;
        if (f == 2048) {
            z = make_float2(0.0f, 0.0f);
        } else {
            int m = 4096 - f;                    // 1..2047
            float2 y1 = s1[m];
            float2 y2 = s2[m];
            z = make_float2(y1.x + y2.y, y2.x - y1.y);  // conj(Y1)+i*conj(Y2)
        }
        a[__brev((unsigned)f) >> 20] = z;
    }
    __syncthreads();
    for (int s = 1; s <= 12; ++s) {
        int half = 1 << (s - 1);
        int tws  = 12 - s;
        for (int j = t; j < 2048; j += 256) {
            int k = j & (half - 1);
            int base = ((j >> (s - 1)) << s) + k;
            float2 w = tw[k << tws];
            w.y = -w.y;                          // conjugate: inverse
            float2 x0 = a[base];
            float2 x1 = a[base + half];
            float tr = w.x * x1.x - w.y * x1.y;
            float ti = w.x * x1.y + w.y * x1.x;
            a[base]        = make_float2(x0.x + tr, x0.y + ti);
            a[base + half] = make_float2(x0.x - tr, x0.y - ti);
        }
        __syncthreads();
    }
    float bias1 = sb0[layer*NH+o]   + sb1[layer*NH+o]   + sb2[layer*NH+o];
    float bias2 = sb0[layer*NH+o+1] + sb1[layer*NH+o+1] + sb2[layer*NH+o+1];
    float* d1 = sout + (size_t)(2*p)   * LEN;
    float* d2 = sout + (size_t)(2*p+1) * LEN;
    const float sc = 1.0f / 4096.0f;
    for (int j = 0; j < 16; ++j) {
        int l = t + j * 256;
        float2 zz = a[l];
        d1[l] = zz.x * sc + bias1;
        d2[l] = zz.y * sc + bias2;
    }
}

// ---------------------------------------------------------------------------
// spectral matmul v3: latency-bound fix = 4x more blocks (o split 4 ways).
//   X: [row=b*64+i][f]  (fft_fwd output)        read 4x (cheap, 128 MB)
//   W: streamed once (117 MB, dominant)         never replicated
//   Y: [row=b*64+o][f]  (fft_inv input)         direct coalesced stores
// Block = 8 f-bins x 16 o x 32 b, full i=64 reduction. Grid 256x4 = 1024
// blocks -> 4 blocks/CU resident (LDS 28.8 KB, VGPR capped via launch_bounds)
// vs round-2's 2 blocks/CU at 10% occupancy.
// All global accesses lane-contiguous: lanes ff=0..7 cover one 64B f-run.
__global__ __launch_bounds__(256, 4) void specmm_k(
        const float2* __restrict__ X, float2* __restrict__ Y,
        const float* __restrict__ w0, const float* __restrict__ w1,
        const float* __restrict__ w2, int layer) {
    __shared__ float2 Xs[8][33][9];   // [i][b][f] (+pads vs bank conflicts)
    __shared__ float2 Ws[8][17][9];   // [i][o][f] (+pads)
    int f0 = blockIdx.x * 8;
    int og = blockIdx.y;              // 0..3 : o-group of 16
    int t  = threadIdx.x;
    int ff = t & 7;                   // f offset (shared by all roles)
    int u  = t >> 3;                  // 0..31
    int b0  = (u & 7) * 4;            // compute: 4 b rows
    int oo0 = (u >> 3) * 4;           // compute: 4 o cols (of 16)
    float2 acc[4][4];
    for (int bb = 0; bb < 4; ++bb)
        for (int oo = 0; oo < 4; ++oo)
            acc[bb][oo] = make_float2(0.0f, 0.0f);

    const float2* w0b = (const float2*)w0 + (size_t)layer * NH * NH * 512;
    const float2* w1b = (const float2*)w1 + (size_t)layer * NH * NH * 1024;
    const float2* w2b = (const float2*)w2 + (size_t)layer * NH * NH * 2048;
    const bool has0 = (f0 < 512);
    const bool has1 = (f0 < 1024);

    const int slot = u;               // X staging: b row 0..31
    const int os   = u & 15;          // W staging: o-sub 0..15
    const int jh   = u >> 4;          // W staging: i-half 0..1

    float2 xv[8], wv[4];
    #define LOAD_CHUNK(ic_)                                                     \
    {                                                                           \
        _Pragma("unroll")                                                       \
        for (int j = 0; j < 8; ++j)                                             \
            xv[j] = X[((size_t)slot * NH + (ic_) * 8 + j) * 2048 + f0 + ff];    \
        _Pragma("unroll")                                                       \
        for (int j = 0; j < 4; ++j) {                                           \
            const size_t io = (size_t)((ic_) * 8 + jh * 4 + j) * NH + (og * 16 + os); \
            float2 q = w2b[io * 2048 + f0 + ff];                                \
            if (has1) { float2 q1 = w1b[io * 1024 + f0 + ff]; q.x += q1.x; q.y += q1.y; } \
            if (has0) { float2 q0 = w0b[io * 512  + f0 + ff]; q.x += q0.x; q.y += q0.y; } \
            wv[j] = q;                                                          \
        }                                                                       \
    }

    LOAD_CHUNK(0);
    for (int ic = 0; ic < 8; ++ic) {
        __syncthreads();                          // previous compute done
        #pragma unroll
        for (int j = 0; j < 8; ++j) Xs[j][slot][ff] = xv[j];
        #pragma unroll
        for (int j = 0; j < 4; ++j) Ws[jh * 4 + j][os][ff] = wv[j];
        __syncthreads();
        if (ic < 7) LOAD_CHUNK(ic + 1);           // prefetch next; hidden by compute
        #pragma unroll
        for (int ii = 0; ii < 8; ++ii) {
            float2 xr[4], wr[4];
            #pragma unroll
            for (int bb = 0; bb < 4; ++bb) xr[bb] = Xs[ii][b0 + bb][ff];
            #pragma unroll
            for (int oo = 0; oo < 4; ++oo) wr[oo] = Ws[ii][oo0 + oo][ff];
            #pragma unroll
            for (int bb = 0; bb < 4; ++bb)
                #pragma unroll
                for (int oo = 0; oo < 4; ++oo) {
                    acc[bb][oo].x += xr[bb].x * wr[oo].x - xr[bb].y * wr[oo].y;
                    acc[bb][oo].y += xr[bb].x * wr[oo].y + xr[bb].y * wr[oo].x;
                }
        }
    }
    #undef LOAD_CHUNK

    // direct stores: for fixed (bb,oo) the wave's lanes cover 8 rows x 64B
    // f-runs -> fully coalesced; no LDS re-stage needed.
    #pragma unroll
    for (int bb = 0; bb < 4; ++bb)
        #pragma unroll
        for (int oo = 0; oo < 4; ++oo)
            Y[((size_t)(b0 + bb) * NH + og * 16 + oo0 + oo) * 2048 + f0 + ff] = acc[bb][oo];
}

// ---------------------------------------------------------------------------
// fused conv1+gelu+conv2+residual: per (b,l), h stays in registers.
// Last layer: fuse the decoder (dot with dec_w) and write out directly.
__global__ __launch_bounds__(256) void conv_fused_k(
        const float* __restrict__ s,
        const float* __restrict__ c1w, const float* __restrict__ c1b,
        const float* __restrict__ c2w, const float* __restrict__ c2b,
        int layer, float* __restrict__ v,
        const float* __restrict__ dw, const float* __restrict__ db,
        float* __restrict__ out, int last) {
    int tid = blockIdx.x * 256 + threadIdx.x;
    int b = tid >> 12;
    int l = tid & (LEN - 1);
    float xr[NH];
    #pragma unroll
    for (int i = 0; i < NH; ++i) xr[i] = s[((size_t)b * NH + i) * LEN + l];
    const float* w1 = c1w + (size_t)layer * NH * NH;
    const float* b1 = c1b + layer * NH;
    const float* w2 = c2w + (size_t)layer * NH * NH;
    const float* b2 = c2b + layer * NH;
    float acc2[NH];
    #pragma unroll
    for (int o = 0; o < NH; ++o) acc2[o] = b2[o];
    for (int i = 0; i < NH; ++i) {               // not unrolled: keeps I-size sane
        float acc = b1[i];
        #pragma unroll
        for (int k = 0; k < NH; ++k) acc += w1[i * NH + k] * xr[k];
        float cc = 0.7978845608028654f * (acc + 0.044715f * acc * acc * acc);
        float e  = __expf(2.0f * cc);
        float th = 1.0f - 2.0f / (e + 1.0f);
        float h  = 0.5f * acc * (1.0f + th);
        #pragma unroll
        for (int o = 0; o < NH; ++o) acc2[o] += w2[o * NH + i] * h;
    }
    if (!last) {
        #pragma unroll
        for (int o = 0; o < NH; ++o) {
            size_t idx = ((size_t)b * NH + o) * LEN + l;
            v[idx] = v[idx] + acc2[o];
        }
    } else {
        float acc = db[0];
        #pragma unroll
        for (int o = 0; o < NH; ++o) {
            size_t idx = ((size_t)b * NH + o) * LEN + l;
            acc += dw[o] * (v[idx] + acc2[o]);
        }
        out[(size_t)b * LEN + l] = acc;
    }
}

// ---------------------------------------------------------------------------
extern "C" void kernel_launch(void* const* d_in, const int* in_sizes, int n_in,
                              void* d_out, int out_size, void* d_ws, size_t ws_size,
                              hipStream_t stream) {
    const float* u_in   = (const float*)d_in[0];
    const float* x_in   = (const float*)d_in[1];
    const float* enc_w  = (const float*)d_in[2];
    const float* enc_b  = (const float*)d_in[3];
    const float* dec_w  = (const float*)d_in[4];
    const float* dec_b  = (const float*)d_in[5];
    const float* conv1w = (const float*)d_in[6];
    const float* conv1b = (const float*)d_in[7];
    const float* conv2w = (const float*)d_in[8];
    const float* conv2b = (const float*)d_in[9];
    const float* sw0    = (const float*)d_in[10];
    const float* sb0    = (const float*)d_in[11];
    const float* sw1    = (const float*)d_in[12];
    const float* sb1    = (const float*)d_in[13];
    const float* sw2    = (const float*)d_in[14];
    const float* sb2    = (const float*)d_in[15];

    const size_t CPLX = (size_t)2048 * 2048;
    const size_t REAL = (size_t)NB * NH * LEN;
    char* base = (char*)d_ws;
    float2* tw   = (float2*)base;
    float2* bufA = (float2*)(base + 16384);      // Xt: [row][f]
    float2* bufB = bufA + CPLX;                  // Yt: [row][f]
    float*  sbuf = (float*)(bufB + CPLX);
    float*  vbuf = sbuf + REAL;
    size_t need = 16384 + 2 * CPLX * sizeof(float2) + 2 * REAL * sizeof(float);
    if (ws_size < need) return;

    fill_tw<<<8, 256, 0, stream>>>(tw);
    encoder_k<<<(NB * LEN) / 256, 256, 0, stream>>>(x_in, u_in, enc_w, enc_b, vbuf);

    for (int l = 0; l < NLAYER; ++l) {
        fft_fwd_k  <<<NB * NH / 2, 256, 0, stream>>>(vbuf, bufA, tw);
        specmm_k   <<<dim3(NF / 8, 4), 256, 0, stream>>>(bufA, bufB, sw0, sw1, sw2, l);
        fft_inv_k  <<<NB * NH / 2, 256, 0, stream>>>(bufB, sbuf, tw, sb0, sb1, sb2, l);
        conv_fused_k<<<(NB * LEN) / 256, 256, 0, stream>>>(sbuf, conv1w, conv1b,
                                                           conv2w, conv2b, l, vbuf,
                                                           dec_w, dec_b, (float*)d_out,
                                                           l == NLAYER - 1);
    }
}

// Round 4
// 1494.189 us; speedup vs baseline: 1.3520x; 1.3520x over previous
//
#include <hip/hip_runtime.h>
#include <math.h>

#ifndef M_PI
#define M_PI 3.14159265358979323846
#endif

#define LEN   4096
#define NB    32
#define NH    64
#define NF    2048   // modes stored (bins 0..2047)
#define NLAYER 4

// ---------------------------------------------------------------------------
// twiddle table: tw[k] = exp(-2*pi*i*k/4096), k = 0..2047
__global__ __launch_bounds__(256) void fill_tw(float2* __restrict__ tw) {
    int k = blockIdx.x * 256 + threadIdx.x;
    if (k < 2048) {
        double ang = -2.0 * M_PI * (double)k / 4096.0;
        tw[k] = make_float2((float)cos(ang), (float)sin(ang));
    }
}

// ---------------------------------------------------------------------------
// encoder
__global__ __launch_bounds__(256) void encoder_k(
        const float* __restrict__ x, const float* __restrict__ u,
        const float* __restrict__ ew, const float* __restrict__ eb,
        float* __restrict__ v) {
    int tid = blockIdx.x * 256 + threadIdx.x;
    int b = tid >> 12;
    int l = tid & (LEN - 1);
    float xv = x[(size_t)b * LEN + l];
    float u0 = u[((size_t)b * 3 + 0) * LEN + l];
    float u1 = u[((size_t)b * 3 + 1) * LEN + l];
    float u2 = u[((size_t)b * 3 + 2) * LEN + l];
    for (int h = 0; h < NH; ++h) {
        float a = eb[h] + ew[h*4+0]*xv + ew[h*4+1]*u0 + ew[h*4+2]*u1 + ew[h*4+3]*u2;
        v[((size_t)b * NH + h) * LEN + l] = a;
    }
}

// ---------------------------------------------------------------------------
// forward FFT, REAL-PAIR PACKED: block p handles rows 2p, 2p+1.
// Output is ROW-MAJOR: Xt[row][f], f = 0..2047 (directly consumed by specmm).
__global__ __launch_bounds__(256) void fft_fwd_k(
        const float* __restrict__ vin, float2* __restrict__ Xt,
        const float2* __restrict__ tw) {
    __shared__ float2 a[4096];
    int p = blockIdx.x;                          // 0..1023
    const float* s1 = vin + (size_t)(2*p)   * LEN;
    const float* s2 = vin + (size_t)(2*p+1) * LEN;
    int t = threadIdx.x;
    for (int j = 0; j < 16; ++j) {
        int idx = t + j * 256;
        int r = __brev((unsigned)idx) >> 20;
        a[r] = make_float2(s1[idx], s2[idx]);
    }
    __syncthreads();
    for (int s = 1; s <= 12; ++s) {
        int half = 1 << (s - 1);
        int tws  = 12 - s;
        for (int j = t; j < 2048; j += 256) {
            int k = j & (half - 1);
            int base = ((j >> (s - 1)) << s) + k;
            float2 w  = tw[k << tws];
            float2 x0 = a[base];
            float2 x1 = a[base + half];
            float tr = w.x * x1.x - w.y * x1.y;
            float ti = w.x * x1.y + w.y * x1.x;
            a[base]        = make_float2(x0.x + tr, x0.y + ti);
            a[base + half] = make_float2(x0.x - tr, x0.y - ti);
        }
        __syncthreads();
    }
    float2* d1 = Xt + (size_t)(2*p)   * NF;
    float2* d2 = Xt + (size_t)(2*p+1) * NF;
    for (int j = 0; j < 8; ++j) {
        int f = t + j * 256;                     // 0..2047
        float2 Zf = a[f];
        float2 Zm = a[(4096 - f) & 4095];
        d1[f] = make_float2(0.5f * (Zf.x + Zm.x), 0.5f * (Zf.y - Zm.y));
        d2[f] = make_float2(0.5f * (Zf.y + Zm.y), 0.5f * (Zm.x - Zf.x));
    }
}

// ---------------------------------------------------------------------------
// inverse FFT, REAL-PAIR PACKED: block p produces rows 2p, 2p+1.
// Input is ROW-MAJOR: Yt[row][f] (directly produced by specmm).
__global__ __launch_bounds__(256) void fft_inv_k(
        const float2* __restrict__ Yt, float* __restrict__ sout,
        const float2* __restrict__ tw,
        const float* __restrict__ sb0, const float* __restrict__ sb1,
        const float* __restrict__ sb2, int layer) {
    __shared__ float2 a[4096];
    int p = blockIdx.x;                          // 0..1023
    int o = (2 * p) & (NH - 1);                  // even o
    const float2* s1 = Yt + (size_t)(2*p)   * NF;
    const float2* s2 = Yt + (size_t)(2*p+1) * NF;
    int t = threadIdx.x;
    for (int j = 0; j < 8; ++j) {
        int f = t + j * 256;                     // 0..2047
        float2 y1 = s1[f];
        float2 y2 = s2[f];
        float2 z;
        if (f == 0) z = make_float2(y1.x, y2.x);
        else        z = make_float2(y1.x - y2.y, y1.y + y2.x);
        a[__brev((unsigned)f) >> 20] = z;
    }
    for (int j = 0; j < 8; ++j) {
        int f = 2048 + t + j * 256;              // 2048..4095
        float2 z;
        if (f == 2048) {
            z = make_float2(0.0f, 0.0f);
        } else {
            int m = 4096 - f;                    // 1..2047
            float2 y1 = s1[m];
            float2 y2 = s2[m];
            z = make_float2(y1.x + y2.y, y2.x - y1.y);  // conj(Y1)+i*conj(Y2)
        }
        a[__brev((unsigned)f) >> 20] = z;
    }
    __syncthreads();
    for (int s = 1; s <= 12; ++s) {
        int half = 1 << (s - 1);
        int tws  = 12 - s;
        for (int j = t; j < 2048; j += 256) {
            int k = j & (half - 1);
            int base = ((j >> (s - 1)) << s) + k;
            float2 w = tw[k << tws];
            w.y = -w.y;                          // conjugate: inverse
            float2 x0 = a[base];
            float2 x1 = a[base + half];
            float tr = w.x * x1.x - w.y * x1.y;
            float ti = w.x * x1.y + w.y * x1.x;
            a[base]        = make_float2(x0.x + tr, x0.y + ti);
            a[base + half] = make_float2(x0.x - tr, x0.y - ti);
        }
        __syncthreads();
    }
    float bias1 = sb0[layer*NH+o]   + sb1[layer*NH+o]   + sb2[layer*NH+o];
    float bias2 = sb0[layer*NH+o+1] + sb1[layer*NH+o+1] + sb2[layer*NH+o+1];
    float* d1 = sout + (size_t)(2*p)   * LEN;
    float* d2 = sout + (size_t)(2*p+1) * LEN;
    const float sc = 1.0f / 4096.0f;
    for (int j = 0; j < 16; ++j) {
        int l = t + j * 256;
        float2 zz = a[l];
        d1[l] = zz.x * sc + bias1;
        d2[l] = zz.y * sc + bias2;
    }
}

// ---------------------------------------------------------------------------
// spectral matmul v4: o-split-4 grid (1024 blocks) + NO VGPR CAP (round-3's
// launch_bounds(256,4) forced VGPR=64 -> 374 MB of scratch spills) + block-id
// swizzle so heavy f-tiles (f0<512: 3 W streams) spread across CUs instead of
// piling onto CUs 0..63 (round-2's 2x tail), and the 4 og-siblings of an
// f-tile are dispatch-adjacent for X L2/L3 reuse.
//   X: [row=b*64+i][f]   W: streamed once   Y: direct coalesced stores
// Block = 8 f-bins x 16 o x 32 b, full i=64 reduction.
__global__ __launch_bounds__(256) void specmm_k(
        const float2* __restrict__ X, float2* __restrict__ Y,
        const float* __restrict__ w0, const float* __restrict__ w1,
        const float* __restrict__ w2, int layer) {
    __shared__ float2 Xs[8][33][9];   // [i][b][f] (+pads vs bank conflicts)
    __shared__ float2 Ws[8][17][9];   // [i][o][f] (+pads)
    // swizzled decode: n -> og (o-group), ftile with heavy tiles interleaved
    int n  = blockIdx.x;              // 0..1023
    int og = n & 3;                   // siblings adjacent -> X reuse in L2/L3
    int q  = n >> 2;                  // 0..255
    int ftile = (q & 3) * 64 + (q >> 2);   // heavy (ftile<64) every 4th q
    int f0 = ftile * 8;
    int t  = threadIdx.x;
    int ff = t & 7;                   // f offset (shared by all roles)
    int u  = t >> 3;                  // 0..31
    int b0  = (u & 7) * 4;            // compute: 4 b rows
    int oo0 = (u >> 3) * 4;           // compute: 4 o cols (of 16)
    float2 acc[4][4];
    for (int bb = 0; bb < 4; ++bb)
        for (int oo = 0; oo < 4; ++oo)
            acc[bb][oo] = make_float2(0.0f, 0.0f);

    const float2* w0b = (const float2*)w0 + (size_t)layer * NH * NH * 512;
    const float2* w1b = (const float2*)w1 + (size_t)layer * NH * NH * 1024;
    const float2* w2b = (const float2*)w2 + (size_t)layer * NH * NH * 2048;
    const bool has0 = (f0 < 512);
    const bool has1 = (f0 < 1024);

    const int slot = u;               // X staging: b row 0..31
    const int os   = u & 15;          // W staging: o-sub 0..15
    const int jh   = u >> 4;          // W staging: i-half 0..1

    float2 xv[8], wv[4];
    #define LOAD_CHUNK(ic_)                                                     \
    {                                                                           \
        _Pragma("unroll")                                                       \
        for (int j = 0; j < 8; ++j)                                             \
            xv[j] = X[((size_t)slot * NH + (ic_) * 8 + j) * 2048 + f0 + ff];    \
        _Pragma("unroll")                                                       \
        for (int j = 0; j < 4; ++j) {                                           \
            const size_t io = (size_t)((ic_) * 8 + jh * 4 + j) * NH + (og * 16 + os); \
            float2 q2 = w2b[io * 2048 + f0 + ff];                               \
            if (has1) { float2 q1 = w1b[io * 1024 + f0 + ff]; q2.x += q1.x; q2.y += q1.y; } \
            if (has0) { float2 q0 = w0b[io * 512  + f0 + ff]; q2.x += q0.x; q2.y += q0.y; } \
            wv[j] = q2;                                                         \
        }                                                                       \
    }

    LOAD_CHUNK(0);
    for (int ic = 0; ic < 8; ++ic) {
        __syncthreads();                          // previous compute done
        #pragma unroll
        for (int j = 0; j < 8; ++j) Xs[j][slot][ff] = xv[j];
        #pragma unroll
        for (int j = 0; j < 4; ++j) Ws[jh * 4 + j][os][ff] = wv[j];
        __syncthreads();
        if (ic < 7) LOAD_CHUNK(ic + 1);           // prefetch next; hidden by compute
        #pragma unroll
        for (int ii = 0; ii < 8; ++ii) {
            float2 xr[4], wr[4];
            #pragma unroll
            for (int bb = 0; bb < 4; ++bb) xr[bb] = Xs[ii][b0 + bb][ff];
            #pragma unroll
            for (int oo = 0; oo < 4; ++oo) wr[oo] = Ws[ii][oo0 + oo][ff];
            #pragma unroll
            for (int bb = 0; bb < 4; ++bb)
                #pragma unroll
                for (int oo = 0; oo < 4; ++oo) {
                    acc[bb][oo].x += xr[bb].x * wr[oo].x - xr[bb].y * wr[oo].y;
                    acc[bb][oo].y += xr[bb].x * wr[oo].y + xr[bb].y * wr[oo].x;
                }
        }
    }
    #undef LOAD_CHUNK

    // direct stores: for fixed (bb,oo) the wave's 8-lane groups cover 8 rows
    // of 64B f-runs -> coalesced; no LDS re-stage.
    #pragma unroll
    for (int bb = 0; bb < 4; ++bb)
        #pragma unroll
        for (int oo = 0; oo < 4; ++oo)
            Y[((size_t)(b0 + bb) * NH + og * 16 + oo0 + oo) * 2048 + f0 + ff] = acc[bb][oo];
}

// ---------------------------------------------------------------------------
// fused conv1+gelu+conv2+residual: per (b,l), h stays in registers.
// Last layer: fuse the decoder (dot with dec_w) and write out directly.
__global__ __launch_bounds__(256) void conv_fused_k(
        const float* __restrict__ s,
        const float* __restrict__ c1w, const float* __restrict__ c1b,
        const float* __restrict__ c2w, const float* __restrict__ c2b,
        int layer, float* __restrict__ v,
        const float* __restrict__ dw, const float* __restrict__ db,
        float* __restrict__ out, int last) {
    int tid = blockIdx.x * 256 + threadIdx.x;
    int b = tid >> 12;
    int l = tid & (LEN - 1);
    float xr[NH];
    #pragma unroll
    for (int i = 0; i < NH; ++i) xr[i] = s[((size_t)b * NH + i) * LEN + l];
    const float* w1 = c1w + (size_t)layer * NH * NH;
    const float* b1 = c1b + layer * NH;
    const float* w2 = c2w + (size_t)layer * NH * NH;
    const float* b2 = c2b + layer * NH;
    float acc2[NH];
    #pragma unroll
    for (int o = 0; o < NH; ++o) acc2[o] = b2[o];
    for (int i = 0; i < NH; ++i) {               // not unrolled: keeps I-size sane
        float acc = b1[i];
        #pragma unroll
        for (int k = 0; k < NH; ++k) acc += w1[i * NH + k] * xr[k];
        float cc = 0.7978845608028654f * (acc + 0.044715f * acc * acc * acc);
        float e  = __expf(2.0f * cc);
        float th = 1.0f - 2.0f / (e + 1.0f);
        float h  = 0.5f * acc * (1.0f + th);
        #pragma unroll
        for (int o = 0; o < NH; ++o) acc2[o] += w2[o * NH + i] * h;
    }
    if (!last) {
        #pragma unroll
        for (int o = 0; o < NH; ++o) {
            size_t idx = ((size_t)b * NH + o) * LEN + l;
            v[idx] = v[idx] + acc2[o];
        }
    } else {
        float acc = db[0];
        #pragma unroll
        for (int o = 0; o < NH; ++o) {
            size_t idx = ((size_t)b * NH + o) * LEN + l;
            acc += dw[o] * (v[idx] + acc2[o]);
        }
        out[(size_t)b * LEN + l] = acc;
    }
}

// ---------------------------------------------------------------------------
extern "C" void kernel_launch(void* const* d_in, const int* in_sizes, int n_in,
                              void* d_out, int out_size, void* d_ws, size_t ws_size,
                              hipStream_t stream) {
    const float* u_in   = (const float*)d_in[0];
    const float* x_in   = (const float*)d_in[1];
    const float* enc_w  = (const float*)d_in[2];
    const float* enc_b  = (const float*)d_in[3];
    const float* dec_w  = (const float*)d_in[4];
    const float* dec_b  = (const float*)d_in[5];
    const float* conv1w = (const float*)d_in[6];
    const float* conv1b = (const float*)d_in[7];
    const float* conv2w = (const float*)d_in[8];
    const float* conv2b = (const float*)d_in[9];
    const float* sw0    = (const float*)d_in[10];
    const float* sb0    = (const float*)d_in[11];
    const float* sw1    = (const float*)d_in[12];
    const float* sb1    = (const float*)d_in[13];
    const float* sw2    = (const float*)d_in[14];
    const float* sb2    = (const float*)d_in[15];

    const size_t CPLX = (size_t)2048 * 2048;
    const size_t REAL = (size_t)NB * NH * LEN;
    char* base = (char*)d_ws;
    float2* tw   = (float2*)base;
    float2* bufA = (float2*)(base + 16384);      // Xt: [row][f]
    float2* bufB = bufA + CPLX;                  // Yt: [row][f]
    float*  sbuf = (float*)(bufB + CPLX);
    float*  vbuf = sbuf + REAL;
    size_t need = 16384 + 2 * CPLX * sizeof(float2) + 2 * REAL * sizeof(float);
    if (ws_size < need) return;

    fill_tw<<<8, 256, 0, stream>>>(tw);
    encoder_k<<<(NB * LEN) / 256, 256, 0, stream>>>(x_in, u_in, enc_w, enc_b, vbuf);

    for (int l = 0; l < NLAYER; ++l) {
        fft_fwd_k  <<<NB * NH / 2, 256, 0, stream>>>(vbuf, bufA, tw);
        specmm_k   <<<1024, 256, 0, stream>>>(bufA, bufB, sw0, sw1, sw2, l);
        fft_inv_k  <<<NB * NH / 2, 256, 0, stream>>>(bufB, sbuf, tw, sb0, sb1, sb2, l);
        conv_fused_k<<<(NB * LEN) / 256, 256, 0, stream>>>(sbuf, conv1w, conv1b,
                                                           conv2w, conv2b, l, vbuf,
                                                           dec_w, dec_b, (float*)d_out,
                                                           l == NLAYER - 1);
    }
}